// Round 3
// baseline (146.858 us; speedup 1.0000x reference)
//
#include <hip/hip_runtime.h>

// VectorQuantizer: B=16, D=64, H=64, W=64, K=1024
#define DD 64
#define KK 1024
#define NPTS 65536
#define TOTAL 4194304

// Output layout (flat f32): quantized[4194304], L1, L2, idx[65536]
#define OFF_L1 4194304
#define OFF_L2 4194305
#define OFF_IDX 4194306

// ws layout (bytes): [0] f32 sum, [8] u32 ticket, enh @ float 64 (byte 256),
// ehT @ byte 65536 (128KB), elT @ byte 196608 (128KB). (<=328KB used)
#define WS_ENH_F 64
#define WS_EHT_BYTE 65536
#define WS_ELT_BYTE (65536 + 131072)

// score = dot(x,e) + 512 - ||e||^2/2  (argmax == argmin distance; +512 keeps
// all scores positive so float bits are monotone -> packed uint compare).
// Rescue margin: 32-ulp granule (<=2e-3) + bf16x3 err (~6e-4) + slack.
#define MARGIN_S 0.006f

typedef __attribute__((ext_vector_type(8))) short short8;
typedef __attribute__((ext_vector_type(4))) float f32x4;

__device__ __forceinline__ unsigned short bf16_rne(float f) {
    unsigned b = __float_as_uint(f);
    return (unsigned short)((b + 0x7FFFu + ((b >> 16) & 1u)) >> 16);
}
__device__ __forceinline__ float bf16_to_f(unsigned short h) {
    return __uint_as_float(((unsigned)h) << 16);
}
__device__ __forceinline__ unsigned umax(unsigned a, unsigned b) { return a > b ? a : b; }
__device__ __forceinline__ unsigned umin(unsigned a, unsigned b) { return a < b ? a : b; }
// async global->LDS DMA, 16B per lane; LDS dest = wave-uniform base + lane*16
__device__ __forceinline__ void gld_lds16(const void* g, void* l) {
    __builtin_amdgcn_global_load_lds(
        (const __attribute__((address_space(1))) void*)g,
        (__attribute__((address_space(3))) void*)l, 16, 0, 0);
}
// swizzled position of element d within a 64-elem row r (16B-granule XOR key)
__device__ __forceinline__ int swz(int r, int d) {
    return ((d & ~7) ^ ((r & 7) << 3)) | (d & 7);
}

// ---------- kernel 1: enh + swizzled bf16 hi/lo codebook [k][64] ----------
__global__ __launch_bounds__(256) void prep_kernel(const float* __restrict__ e,
                                                   float* __restrict__ enh,
                                                   unsigned short* __restrict__ ehT,
                                                   unsigned short* __restrict__ elT,
                                                   float* __restrict__ sum,
                                                   unsigned* __restrict__ tick) {
    const int tid = threadIdx.x;
    if (blockIdx.x == 0 && tid == 0) { *sum = 0.f; *tick = 0u; }
    const int wave = tid >> 6, lane = tid & 63;
    const int k = blockIdx.x * 4 + wave;      // this wave's code
    const float v = e[lane * KK + k];         // lane = d
    const unsigned short h = bf16_rne(v);
    const unsigned short l = bf16_rne(v - bf16_to_f(h));
    const int pos = k * 64 + swz(k, lane);
    ehT[pos] = h;
    elT[pos] = l;
    float s2 = v * v;
#pragma unroll
    for (int m = 32; m > 0; m >>= 1) s2 += __shfl_down(s2, m, 64);
    if (lane == 0) enh[k] = 512.0f - 0.5f * s2;
}

// ---------- kernel 2: MFMA bf16x3 + packed-key argmax + in-block exact rescue
//            + quantize (bf16 hi+lo reconstruct) + loss via score identity ----------
// 256 thr = 4 waves; block = 64 pts x 1024 codes (16 tiles of 64 codes).
// TRIPLE-buffered codebook tiles + counted s_waitcnt vmcnt(4) + raw s_barrier:
// DMA(kt) is issued two compute windows before its wait, so the per-tile
// vmcnt(0) drain of the __syncthreads structure (the r0 bottleneck, ~60% of
// time) is eliminated. No launch_bounds min-occupancy: (256,5)/(256,4) forced
// VGPR 48/56 and AGPR-shuffle/spill regressions (dur 58->89/78us).
// In-loop vmcnt audit: loop body has NO other vmcnt ops (enh is read from LDS,
// x-norm partials from LDS); steady state outstanding at the wait =
// DMA(kt)+DMA(kt+1) = 8 -> vmcnt(4) completes DMA(kt); kt=15 uses vmcnt(0).
__global__ __launch_bounds__(256) void vq_gemm(const float* __restrict__ x,
                                               const float* __restrict__ e,
                                               const float* __restrict__ enh,
                                               const unsigned short* __restrict__ ehT,
                                               const unsigned short* __restrict__ elT,
                                               float* __restrict__ out,
                                               float* __restrict__ sum,
                                               unsigned* __restrict__ tick) {
    __shared__ __align__(16) char ebuf[3 * 16384];   // 48KB: 3 codebook tile bufs
    __shared__ float enh_lds[1024];                  // 4KB bias table (no vm in loop)
    __shared__ float xnp4[256];                      // 1KB ||x||^2 partials (persist)

    // post-loop aliases into ebuf (ebuf dead after the post-loop __syncthreads)
    float* mv1 = (float*)ebuf;          // [128]
    float* mv2 = mv1 + 128;             // [128]
    int*   mi1 = (int*)(mv2 + 128);     // [128]
    int*   ks  = mi1 + 128;             // [64]
    float* lv  = (float*)(ks + 64);     // [64]  per-point loss term
    float* xp  = lv + 64;               // [64]  rescue point
    int*   rl  = (int*)(xp + 64);       // [64]  ambiguous-point list
    int*   rn  = rl + 64;               // [1]
    float* rv  = (float*)(rn + 1);      // [4]
    int*   ri  = (int*)(rv + 4);        // [4]

    const int tid = threadIdx.x;
    const int wave = tid >> 6, lane = tid & 63;
    const int n0 = blockIdx.x * 64;
    const int b = n0 >> 12;
    const int hw0 = n0 & 4095;

    const char* ehTb = (const char*)ehT;
    const char* elTb = (const char*)elT;
    const int lofs = wave * 1024 + lane * 16;   // per-lane byte offset in a pass

    // issue tile-0 and tile-1 DMA immediately (land during x-prep; the
    // prologue __syncthreads drains them before the loop starts)
#pragma unroll
    for (int t0 = 0; t0 < 2; ++t0) {
        char* db = ebuf + t0 * 16384;
        const char* sH = ehTb + t0 * 8192 + lofs;
        const char* sL = elTb + t0 * 8192 + lofs;
        gld_lds16(sH,        db + wave * 1024);
        gld_lds16(sH + 4096, db + 4096 + wave * 1024);
        gld_lds16(sL,        db + 8192 + wave * 1024);
        gld_lds16(sL + 4096, db + 12288 + wave * 1024);
    }

    // enh -> LDS (4 floats/thread, vectorized)
    *(float4*)(enh_lds + tid * 4) = *(const float4*)(enh + tid * 4);

    // ---- x prep: DIRECT coalesced global->reg (no fp32 LDS stage), then
    // bf16 hi/lo pack into buf2. wave w loads d-range [w*16, w*16+16), lane=p.
    unsigned short* xbh = (unsigned short*)(ebuf + 32768);
    unsigned short* xbl = xbh + 4096;
    {
        const float* xs = x + ((b * DD + wave * 16) << 12) + hw0 + lane;
        float xv[16];
        float xn = 0.f;
#pragma unroll
        for (int s = 0; s < 16; ++s) {
            xv[s] = xs[s << 12];            // 256B coalesced per (wave,s)
            xn = fmaf(xv[s], xv[s], xn);
        }
        xnp4[tid] = xn;                     // partial over 16 d's
#pragma unroll
        for (int g = 0; g < 2; ++g) {
            short8 hh, ll;
#pragma unroll
            for (int j = 0; j < 8; ++j) {
                const float f = xv[g * 8 + j];
                const unsigned short h = bf16_rne(f);
                hh[j] = (short)h;
                ll[j] = (short)bf16_rne(f - bf16_to_f(h));
            }
            const int pos = lane * 64 + ((wave * 16 + g * 8) ^ ((lane & 7) << 3));
            *(short8*)(xbh + pos) = hh;
            *(short8*)(xbl + pos) = ll;
        }
    }
    __syncthreads();   // x-bf16 + enh_lds visible; drains DMA(0),DMA(1)

    const int ln15 = lane & 15, q8 = (lane >> 4) * 8;
    const int wp = (wave >> 1) * 32;   // point base of this wave
    const int wc = (wave & 1) * 32;    // code base within tile

    short8 ah[2][2], al[2][2];         // persistent A frags [rf][kc]
#pragma unroll
    for (int rf = 0; rf < 2; ++rf)
#pragma unroll
        for (int kc = 0; kc < 2; ++kc) {
            const int pp = wp + rf * 16 + ln15;
            const int pos = pp * 64 + ((kc * 32 + q8) ^ ((pp & 7) << 3));
            ah[rf][kc] = *(const short8*)(xbh + pos);
            al[rf][kc] = *(const short8*)(xbl + pos);
        }
    __syncthreads();   // frag data in regs everywhere; buf2 reusable for DMA(2)

    unsigned v1u[8], v2u[8];
#pragma unroll
    for (int r = 0; r < 8; ++r) { v1u[r] = 0u; v2u[r] = 0u; }

    for (int kt = 0; kt < 16; ++kt) {
        // counted wait: DMA(kt) done (issued 2 iterations ago; exposure ~0)
        if (kt < 15) asm volatile("s_waitcnt vmcnt(4)" ::: "memory");
        else         asm volatile("s_waitcnt vmcnt(0)" ::: "memory");
        asm volatile("s_barrier" ::: "memory");   // all waves' DMA(kt) done;
        __builtin_amdgcn_sched_barrier(0);        // all compute(kt-1) done
        if (kt < 14) {     // stream tile kt+2 (its buffer was read at kt-1)
            const int nkt = kt + 2;
            char* db = ebuf + (nkt % 3) * 16384;
            const char* sH = ehTb + nkt * 8192 + lofs;
            const char* sL = elTb + nkt * 8192 + lofs;
            gld_lds16(sH,        db + wave * 1024);
            gld_lds16(sH + 4096, db + 4096 + wave * 1024);
            gld_lds16(sL,        db + 8192 + wave * 1024);
            gld_lds16(sL + 4096, db + 12288 + wave * 1024);
        }
        const unsigned short* ebH = (const unsigned short*)(ebuf + (kt % 3) * 16384);
        const unsigned short* ebL = ebH + 4096;

        // acc init = 512 - ||e||^2/2 (biased argmax score), from LDS
        f32x4 acc[2][2];
#pragma unroll
        for (int cf = 0; cf < 2; ++cf) {
            const float ec = enh_lds[kt * 64 + wc + cf * 16 + ln15];
#pragma unroll
            for (int rf = 0; rf < 2; ++rf)
                acc[rf][cf] = (f32x4){ec, ec, ec, ec};
        }

#pragma unroll
        for (int kc = 0; kc < 2; ++kc) {
            short8 bh[2], bl[2];
#pragma unroll
            for (int cf = 0; cf < 2; ++cf) {
                const int c = wc + cf * 16 + ln15;
                const int pos = c * 64 + ((kc * 32 + q8) ^ ((c & 7) << 3));
                bh[cf] = *(const short8*)(ebH + pos);
                bl[cf] = *(const short8*)(ebL + pos);
            }
#pragma unroll
            for (int rf = 0; rf < 2; ++rf)
#pragma unroll
                for (int cf = 0; cf < 2; ++cf) {
                    acc[rf][cf] = __builtin_amdgcn_mfma_f32_16x16x32_bf16(al[rf][kc], bh[cf], acc[rf][cf], 0, 0, 0);
                    acc[rf][cf] = __builtin_amdgcn_mfma_f32_16x16x32_bf16(ah[rf][kc], bl[cf], acc[rf][cf], 0, 0, 0);
                    acc[rf][cf] = __builtin_amdgcn_mfma_f32_16x16x32_bf16(ah[rf][kc], bh[cf], acc[rf][cf], 0, 0, 0);
                }
        }

        // packed-key top-2 per (rf,reg) row: key = (bits|31) ^ col5
        // (low5 = 31^col5 -> umax tie-breaks toward SMALLER col5 = smaller k)
#pragma unroll
        for (int rf = 0; rf < 2; ++rf)
#pragma unroll
            for (int reg = 0; reg < 4; ++reg) {
                const int r = rf * 4 + reg;
                const unsigned k0 = (__float_as_uint(acc[rf][0][reg]) | 31u) ^ (unsigned)(kt * 2 + 0);
                const unsigned k1 = (__float_as_uint(acc[rf][1][reg]) | 31u) ^ (unsigned)(kt * 2 + 1);
                const unsigned a = umax(k0, k1), bb = umin(k0, k1);
                v2u[r] = umax(umax(v2u[r], umin(v1u[r], a)), bb);
                v1u[r] = umax(v1u[r], a);
            }
    }

    __syncthreads();   // all waves done with tile 15 (buf0) -> ebuf aliases safe
    if (tid == 0) *rn = 0;

    // decode + cross-lane merge within the 16 lanes sharing each row-set
#pragma unroll
    for (int r = 0; r < 8; ++r) {
        const unsigned c5 = 31u - (v1u[r] & 31u);
        int col = (int)(c5 >> 1) * 64 + wc + (int)(c5 & 1) * 16 + ln15;
        float val = __uint_as_float(v1u[r] & ~31u);
        float sec = __uint_as_float(v2u[r] & ~31u);
#pragma unroll
        for (int msk = 1; msk < 16; msk <<= 1) {
            const float ov = __shfl_xor(val, msk);
            const int oc = __shfl_xor(col, msk);
            const float os = __shfl_xor(sec, msk);
            sec = fmaxf(fmaxf(sec, os), fminf(val, ov));
            const bool t = (ov > val) || (ov == val && oc < col);
            val = t ? ov : val;
            col = t ? oc : col;
        }
        if (ln15 == 0) {
            const int q = lane >> 4;
            const int h = wave & 1;
            const int pt = wp + (r >> 2) * 16 + q * 4 + (r & 3);
            mv1[pt * 2 + h] = val;
            mi1[pt * 2 + h] = col;
            mv2[pt * 2 + h] = sec;
        }
    }
    __syncthreads();
    if (tid < 64) {   // merge the two code-half waves (argmax, tie -> smaller idx)
        const float va = mv1[tid * 2], vb = mv1[tid * 2 + 1];
        const int ia = mi1[tid * 2], ib = mi1[tid * 2 + 1];
        const bool t = (vb > va) || (vb == va && ib < ia);
        const float bv = t ? vb : va;
        const int bi = t ? ib : ia;
        const float sec = fmaxf(fmaxf(mv2[tid * 2], mv2[tid * 2 + 1]), fminf(va, vb));
        ks[tid] = bi;
        // loss via identity: ||x-e||^2 = ||x||^2 + 1024 - 2*score
        // midpoint decode (|16 = half the 32-ulp truncation granule) -> unbiased
        const float xnp = xnp4[tid] + xnp4[64 + tid] + xnp4[128 + tid] + xnp4[192 + tid];
        const float bmid = __uint_as_float(__float_as_uint(bv) | 16u);
        lv[tid] = xnp + 1024.0f - 2.0f * bmid;
        if (bv - sec < MARGIN_S) {    // ambiguous under granule+bf16x3 bound
            const int w = atomicAdd(rn, 1);
            rl[w] = tid;              // <=64 entries possible
        }
    }
    __syncthreads();

    // ---- in-block exact fp32 rescue (expected ~0.16 items/block) ----
    const int lcnt = *rn;
    for (int it = 0; it < lcnt; ++it) {
        const int pr = rl[it];
        if (tid < 64) xp[tid] = x[((b * DD + tid) << 12) + hw0 + pr];
        __syncthreads();
        float d0 = 0.f, d1 = 0.f, d2 = 0.f, d3 = 0.f;
#pragma unroll 8
        for (int dd = 0; dd < DD; ++dd) {
            const float xd = xp[dd];
            const float4 ev = *(const float4*)(e + dd * KK + tid * 4);
            d0 = fmaf(xd, ev.x, d0);
            d1 = fmaf(xd, ev.y, d1);
            d2 = fmaf(xd, ev.z, d2);
            d3 = fmaf(xd, ev.w, d3);
        }
        const float4 ea = *(const float4*)(enh + tid * 4);
        float bs = d0 + ea.x;
        int bi2 = tid * 4;
        if (d1 + ea.y > bs) { bs = d1 + ea.y; bi2 = tid * 4 + 1; }
        if (d2 + ea.z > bs) { bs = d2 + ea.z; bi2 = tid * 4 + 2; }
        if (d3 + ea.w > bs) { bs = d3 + ea.w; bi2 = tid * 4 + 3; }
#pragma unroll
        for (int m = 1; m < 64; m <<= 1) {
            const float ov = __shfl_xor(bs, m, 64);
            const int oi = __shfl_xor(bi2, m, 64);
            if (ov > bs || (ov == bs && oi < bi2)) { bs = ov; bi2 = oi; }
        }
        if (lane == 0) { rv[wave] = bs; ri[wave] = bi2; }
        __syncthreads();
        if (tid == 0) {
            float gs = rv[0];
            int gi = ri[0];
#pragma unroll
            for (int t2 = 1; t2 < 4; ++t2)
                if (rv[t2] > gs || (rv[t2] == gs && ri[t2] < gi)) { gs = rv[t2]; gi = ri[t2]; }
            ks[pr] = gi;
            const float xnp = xnp4[pr] + xnp4[64 + pr] + xnp4[128 + pr] + xnp4[192 + pr];
            lv[pr] = xnp + 1024.0f - 2.0f * gs;   // exact score
        }
        __syncthreads();
    }

    // ---- idx out + block loss add + ticketed grid finalize ----
    if (tid < 64) {
        out[OFF_IDX + n0 + tid] = (float)ks[tid];
        float lc = lv[tid];
#pragma unroll
        for (int off = 32; off > 0; off >>= 1) lc += __shfl_down(lc, off, 64);
        if (tid == 0) {
            atomicAdd(sum, lc);
            __threadfence();
            const unsigned old = atomicAdd(tick, 1u);
            if (old == (unsigned)(gridDim.x - 1)) {
                const float s = atomicAdd(sum, 0.0f);
                const float m = s * (1.0f / (float)TOTAL);
                out[OFF_L1] = m;   // dictionary_loss
                out[OFF_L2] = m;   // commitment_loss (numerically identical)
            }
        }
    }

    // ---- quantize epilogue: reconstruct e from bf16 hi+lo (err <= ~3e-5) ----
    {
        const int pe = tid & 63, dqr = tid >> 6;
        const int kp = ks[pe];
        const int kx = (kp & 7) << 3;
        float qa[16];
#pragma unroll
        for (int g = 0; g < 2; ++g) {
            const int pos = kp * 64 + ((dqr * 16 + g * 8) ^ kx);
            const short8 h8 = *(const short8*)(ehT + pos);
            const short8 l8 = *(const short8*)(elT + pos);
#pragma unroll
            for (int j = 0; j < 8; ++j)
                qa[g * 8 + j] = bf16_to_f((unsigned short)h8[j]) + bf16_to_f((unsigned short)l8[j]);
        }
        float* ob = out + ((b * DD + dqr * 16) << 12) + hw0 + pe;
#pragma unroll
        for (int s = 0; s < 16; ++s) ob[s << 12] = qa[s];
    }
}

extern "C" void kernel_launch(void* const* d_in, const int* in_sizes, int n_in,
                              void* d_out, int out_size, void* d_ws, size_t ws_size,
                              hipStream_t stream) {
    const float* x = (const float*)d_in[0];      // [16,64,64,64]
    const float* e = (const float*)d_in[1];      // [64,1024]
    float* out = (float*)d_out;

    float* sum = (float*)d_ws;
    unsigned* tick = (unsigned*)d_ws + 2;
    float* enh = (float*)d_ws + WS_ENH_F;
    unsigned short* ehT = (unsigned short*)((char*)d_ws + WS_EHT_BYTE);
    unsigned short* elT = (unsigned short*)((char*)d_ws + WS_ELT_BYTE);

    prep_kernel<<<256, 256, 0, stream>>>(e, enh, ehT, elT, sum, tick);
    vq_gemm<<<NPTS / 64, 256, 0, stream>>>(x, e, enh, ehT, elT, out, sum, tick);
}

// Round 4
// 137.947 us; speedup vs baseline: 1.0646x; 1.0646x over previous
//
#include <hip/hip_runtime.h>

// VectorQuantizer: B=16, D=64, H=64, W=64, K=1024
#define DD 64
#define KK 1024
#define NPTS 65536
#define TOTAL 4194304

// Output layout (flat f32): quantized[4194304], L1, L2, idx[65536]
#define OFF_L1 4194304
#define OFF_L2 4194305
#define OFF_IDX 4194306

// ws layout (bytes): [0] f32 sum, [8] u32 ticket, enh @ float 64 (byte 256),
// ehT @ byte 65536 (128KB), elT @ byte 196608 (128KB). (<=328KB used)
#define WS_ENH_F 64
#define WS_EHT_BYTE 65536
#define WS_ELT_BYTE (65536 + 131072)

// score = dot(x,e) + 512 - ||e||^2/2  (argmax == argmin distance; +512 keeps
// all scores positive so float bits are monotone -> packed uint compare).
// Rescue margin: 32-ulp granule (<=2e-3) + bf16x3 err (~6e-4) + slack.
#define MARGIN_S 0.006f

typedef __attribute__((ext_vector_type(8))) short short8;
typedef __attribute__((ext_vector_type(4))) float f32x4;

__device__ __forceinline__ unsigned short bf16_rne(float f) {
    unsigned b = __float_as_uint(f);
    return (unsigned short)((b + 0x7FFFu + ((b >> 16) & 1u)) >> 16);
}
__device__ __forceinline__ float bf16_to_f(unsigned short h) {
    return __uint_as_float(((unsigned)h) << 16);
}
__device__ __forceinline__ unsigned umax(unsigned a, unsigned b) { return a > b ? a : b; }
__device__ __forceinline__ unsigned umin(unsigned a, unsigned b) { return a < b ? a : b; }
// async global->LDS DMA, 16B per lane; LDS dest = wave-uniform base + lane*16
__device__ __forceinline__ void gld_lds16(const void* g, void* l) {
    __builtin_amdgcn_global_load_lds(
        (const __attribute__((address_space(1))) void*)g,
        (__attribute__((address_space(3))) void*)l, 16, 0, 0);
}
// swizzled position of element d within a 64-elem row r (16B-granule XOR key)
__device__ __forceinline__ int swz(int r, int d) {
    return ((d & ~7) ^ ((r & 7) << 3)) | (d & 7);
}

// ---------- kernel 1: enh + swizzled bf16 hi/lo codebook [k][64] ----------
__global__ __launch_bounds__(256) void prep_kernel(const float* __restrict__ e,
                                                   float* __restrict__ enh,
                                                   unsigned short* __restrict__ ehT,
                                                   unsigned short* __restrict__ elT,
                                                   float* __restrict__ sum,
                                                   unsigned* __restrict__ tick) {
    const int tid = threadIdx.x;
    if (blockIdx.x == 0 && tid == 0) { *sum = 0.f; *tick = 0u; }
    const int wave = tid >> 6, lane = tid & 63;
    const int k = blockIdx.x * 4 + wave;      // this wave's code
    const float v = e[lane * KK + k];         // lane = d
    const unsigned short h = bf16_rne(v);
    const unsigned short l = bf16_rne(v - bf16_to_f(h));
    const int pos = k * 64 + swz(k, lane);
    ehT[pos] = h;
    elT[pos] = l;
    float s2 = v * v;
#pragma unroll
    for (int m = 32; m > 0; m >>= 1) s2 += __shfl_down(s2, m, 64);
    if (lane == 0) enh[k] = 512.0f - 0.5f * s2;
}

// ---------- kernel 2: MFMA bf16x3 + packed-key argmax + in-block exact rescue
//            + quantize (bf16 hi+lo reconstruct) + loss via score identity ----------
// 256 thr = 4 waves; block = 64 pts x 1024 codes (16 tiles of 64 codes).
// HOT LOOP = the measured-58.5us r0 structure VERBATIM: double-buffered
// global_load_lds + per-tile __syncthreads (compiler-managed waitcnt).
// Lessons encoded here:
//  * NO __launch_bounds__ min-waves: (256,5)->VGPR48 88.7us, (256,4)->VGPR56
//    77.9us, unbounded->VGPR68 58.5us. The cap squeezes the unified VGPR/AGPR
//    file (acc in AGPRs) into shuffles/spills.
//  * NO hand-scheduled vmcnt + sched_barrier(0): r3 = 100us (m141 anti-pattern).
// LDS = 32KB ebuf + 1KB xnp4 = 33792B -> 4 blocks/CU; grid = 4/CU co-resident.
__global__ __launch_bounds__(256) void vq_gemm(const float* __restrict__ x,
                                               const float* __restrict__ e,
                                               const float* __restrict__ enh,
                                               const unsigned short* __restrict__ ehT,
                                               const unsigned short* __restrict__ elT,
                                               float* __restrict__ out,
                                               float* __restrict__ sum,
                                               unsigned* __restrict__ tick) {
    __shared__ __align__(16) char ebuf[2 * 16384];   // 32KB double buffer
    __shared__ float xnp4[256];                      // 1KB ||x||^2 partials

    // post-loop aliases into ebuf[0] (holds tile 14; dead once every wave has
    // passed the post-loop __syncthreads -- kt=15 read only ebuf[1])
    float* mv1 = (float*)ebuf;          // [128]
    float* mv2 = mv1 + 128;             // [128]
    int*   mi1 = (int*)(mv2 + 128);     // [128]
    int*   ks  = mi1 + 128;             // [64]
    float* lv  = (float*)(ks + 64);     // [64]  per-point loss term
    float* xp  = lv + 64;               // [64]  rescue point
    int*   rl  = (int*)(xp + 64);       // [64]  ambiguous-point list
    int*   rn  = rl + 64;               // [1]
    float* rv  = (float*)(rn + 1);      // [4]
    int*   ri  = (int*)(rv + 4);        // [4]

    const int tid = threadIdx.x;
    const int wave = tid >> 6, lane = tid & 63;
    const int n0 = blockIdx.x * 64;
    const int b = n0 >> 12;
    const int hw0 = n0 & 4095;

    const char* ehTb = (const char*)ehT;
    const char* elTb = (const char*)elT;
    const int lofs = wave * 1024 + lane * 16;   // per-lane byte offset in a pass

    // issue tile-0 DMA into buf0 immediately (lands during x-prep)
    {
        char* db = ebuf;
        gld_lds16(ehTb + lofs,        db + wave * 1024);
        gld_lds16(ehTb + 4096 + lofs, db + 4096 + wave * 1024);
        gld_lds16(elTb + lofs,        db + 8192 + wave * 1024);
        gld_lds16(elTb + 4096 + lofs, db + 12288 + wave * 1024);
    }

    // ---- x prep: DIRECT coalesced global->reg (no fp32 LDS stage), then
    // bf16 hi/lo pack into buf1. wave w loads d-range [w*16,w*16+16), lane=p.
    unsigned short* xbh = (unsigned short*)(ebuf + 16384);
    unsigned short* xbl = xbh + 4096;
    {
        const float* xs = x + ((b * DD + wave * 16) << 12) + hw0 + lane;
        float xv[16];
        float xn = 0.f;
#pragma unroll
        for (int s = 0; s < 16; ++s) {
            xv[s] = xs[s << 12];            // 256B coalesced per (wave,s)
            xn = fmaf(xv[s], xv[s], xn);
        }
        xnp4[tid] = xn;                     // partial over this wave's 16 d's
#pragma unroll
        for (int g = 0; g < 2; ++g) {
            short8 hh, ll;
#pragma unroll
            for (int j = 0; j < 8; ++j) {
                const float f = xv[g * 8 + j];
                const unsigned short h = bf16_rne(f);
                hh[j] = (short)h;
                ll[j] = (short)bf16_rne(f - bf16_to_f(h));
            }
            const int pos = lane * 64 + ((wave * 16 + g * 8) ^ ((lane & 7) << 3));
            *(short8*)(xbh + pos) = hh;
            *(short8*)(xbl + pos) = ll;
        }
    }
    __syncthreads();   // x-bf16 visible to all waves (buf1)

    const int ln15 = lane & 15, q8 = (lane >> 4) * 8;
    const int wp = (wave >> 1) * 32;   // point base of this wave
    const int wc = (wave & 1) * 32;    // code base within tile

    short8 ah[2][2], al[2][2];         // persistent A frags [rf][kc]
#pragma unroll
    for (int rf = 0; rf < 2; ++rf)
#pragma unroll
        for (int kc = 0; kc < 2; ++kc) {
            const int pp = wp + rf * 16 + ln15;
            const int pos = pp * 64 + ((kc * 32 + q8) ^ ((pp & 7) << 3));
            ah[rf][kc] = *(const short8*)(xbh + pos);
            al[rf][kc] = *(const short8*)(xbl + pos);
        }
    // NOTE: kt=0's loop-top __syncthreads orders these ds_reads (complete at
    // each wave's barrier arrival) before DMA(1) overwrites buf1.

    unsigned v1u[8], v2u[8];
#pragma unroll
    for (int r = 0; r < 8; ++r) { v1u[r] = 0u; v2u[r] = 0u; }

    for (int kt = 0; kt < 16; ++kt) {
        __syncthreads();   // drains tile-kt DMA + all waves done with kt-1
        if (kt < 15) {     // stream tile kt+1 into the other buffer
            const int nkt = kt + 1;
            char* db = ebuf + (nkt & 1) * 16384;
            const char* sH = ehTb + nkt * 8192 + lofs;
            const char* sL = elTb + nkt * 8192 + lofs;
            gld_lds16(sH,        db + wave * 1024);
            gld_lds16(sH + 4096, db + 4096 + wave * 1024);
            gld_lds16(sL,        db + 8192 + wave * 1024);
            gld_lds16(sL + 4096, db + 12288 + wave * 1024);
        }
        const unsigned short* ebH = (const unsigned short*)(ebuf + (kt & 1) * 16384);
        const unsigned short* ebL = ebH + 4096;

        // acc init = 512 - ||e||^2/2 (biased argmax score)
        f32x4 acc[2][2];
#pragma unroll
        for (int cf = 0; cf < 2; ++cf) {
            const float ec = enh[kt * 64 + wc + cf * 16 + ln15];
#pragma unroll
            for (int rf = 0; rf < 2; ++rf)
                acc[rf][cf] = (f32x4){ec, ec, ec, ec};
        }

#pragma unroll
        for (int kc = 0; kc < 2; ++kc) {
            short8 bh[2], bl[2];
#pragma unroll
            for (int cf = 0; cf < 2; ++cf) {
                const int c = wc + cf * 16 + ln15;
                const int pos = c * 64 + ((kc * 32 + q8) ^ ((c & 7) << 3));
                bh[cf] = *(const short8*)(ebH + pos);
                bl[cf] = *(const short8*)(ebL + pos);
            }
#pragma unroll
            for (int rf = 0; rf < 2; ++rf)
#pragma unroll
                for (int cf = 0; cf < 2; ++cf) {
                    acc[rf][cf] = __builtin_amdgcn_mfma_f32_16x16x32_bf16(al[rf][kc], bh[cf], acc[rf][cf], 0, 0, 0);
                    acc[rf][cf] = __builtin_amdgcn_mfma_f32_16x16x32_bf16(ah[rf][kc], bl[cf], acc[rf][cf], 0, 0, 0);
                    acc[rf][cf] = __builtin_amdgcn_mfma_f32_16x16x32_bf16(ah[rf][kc], bh[cf], acc[rf][cf], 0, 0, 0);
                }
        }

        // packed-key top-2 per (rf,reg) row: key = (bits|31) ^ col5
        // (low5 = 31^col5 -> umax tie-breaks toward SMALLER col5 = smaller k)
#pragma unroll
        for (int rf = 0; rf < 2; ++rf)
#pragma unroll
            for (int reg = 0; reg < 4; ++reg) {
                const int r = rf * 4 + reg;
                const unsigned k0 = (__float_as_uint(acc[rf][0][reg]) | 31u) ^ (unsigned)(kt * 2 + 0);
                const unsigned k1 = (__float_as_uint(acc[rf][1][reg]) | 31u) ^ (unsigned)(kt * 2 + 1);
                const unsigned a = umax(k0, k1), bb = umin(k0, k1);
                v2u[r] = umax(umax(v2u[r], umin(v1u[r], a)), bb);
                v1u[r] = umax(v1u[r], a);
            }
    }

    __syncthreads();   // all waves done with tile 15 (buf1) -> ebuf aliases safe
    if (tid == 0) *rn = 0;

    // decode + cross-lane merge within the 16 lanes sharing each row-set
#pragma unroll
    for (int r = 0; r < 8; ++r) {
        const unsigned c5 = 31u - (v1u[r] & 31u);
        int col = (int)(c5 >> 1) * 64 + wc + (int)(c5 & 1) * 16 + ln15;
        float val = __uint_as_float(v1u[r] & ~31u);
        float sec = __uint_as_float(v2u[r] & ~31u);
#pragma unroll
        for (int msk = 1; msk < 16; msk <<= 1) {
            const float ov = __shfl_xor(val, msk);
            const int oc = __shfl_xor(col, msk);
            const float os = __shfl_xor(sec, msk);
            sec = fmaxf(fmaxf(sec, os), fminf(val, ov));
            const bool t = (ov > val) || (ov == val && oc < col);
            val = t ? ov : val;
            col = t ? oc : col;
        }
        if (ln15 == 0) {
            const int q = lane >> 4;
            const int h = wave & 1;
            const int pt = wp + (r >> 2) * 16 + q * 4 + (r & 3);
            mv1[pt * 2 + h] = val;
            mi1[pt * 2 + h] = col;
            mv2[pt * 2 + h] = sec;
        }
    }
    __syncthreads();
    if (tid < 64) {   // merge the two code-half waves (argmax, tie -> smaller idx)
        const float va = mv1[tid * 2], vb = mv1[tid * 2 + 1];
        const int ia = mi1[tid * 2], ib = mi1[tid * 2 + 1];
        const bool t = (vb > va) || (vb == va && ib < ia);
        const float bv = t ? vb : va;
        const int bi = t ? ib : ia;
        const float sec = fmaxf(fmaxf(mv2[tid * 2], mv2[tid * 2 + 1]), fminf(va, vb));
        ks[tid] = bi;
        // loss via identity: ||x-e||^2 = ||x||^2 + 1024 - 2*score
        // midpoint decode (|16 = half the 32-ulp truncation granule) -> unbiased
        const float xnp = xnp4[tid] + xnp4[64 + tid] + xnp4[128 + tid] + xnp4[192 + tid];
        const float bmid = __uint_as_float(__float_as_uint(bv) | 16u);
        lv[tid] = xnp + 1024.0f - 2.0f * bmid;
        if (bv - sec < MARGIN_S) {    // ambiguous under granule+bf16x3 bound
            const int w = atomicAdd(rn, 1);
            rl[w] = tid;              // <=64 entries possible
        }
    }
    __syncthreads();

    // ---- in-block exact fp32 rescue (expected ~0.16 items/block) ----
    const int lcnt = *rn;
    for (int it = 0; it < lcnt; ++it) {
        const int pr = rl[it];
        if (tid < 64) xp[tid] = x[((b * DD + tid) << 12) + hw0 + pr];
        __syncthreads();
        float d0 = 0.f, d1 = 0.f, d2 = 0.f, d3 = 0.f;
#pragma unroll 8
        for (int dd = 0; dd < DD; ++dd) {
            const float xd = xp[dd];
            const float4 ev = *(const float4*)(e + dd * KK + tid * 4);
            d0 = fmaf(xd, ev.x, d0);
            d1 = fmaf(xd, ev.y, d1);
            d2 = fmaf(xd, ev.z, d2);
            d3 = fmaf(xd, ev.w, d3);
        }
        const float4 ea = *(const float4*)(enh + tid * 4);
        float bs = d0 + ea.x;
        int bi2 = tid * 4;
        if (d1 + ea.y > bs) { bs = d1 + ea.y; bi2 = tid * 4 + 1; }
        if (d2 + ea.z > bs) { bs = d2 + ea.z; bi2 = tid * 4 + 2; }
        if (d3 + ea.w > bs) { bs = d3 + ea.w; bi2 = tid * 4 + 3; }
#pragma unroll
        for (int m = 1; m < 64; m <<= 1) {
            const float ov = __shfl_xor(bs, m, 64);
            const int oi = __shfl_xor(bi2, m, 64);
            if (ov > bs || (ov == bs && oi < bi2)) { bs = ov; bi2 = oi; }
        }
        if (lane == 0) { rv[wave] = bs; ri[wave] = bi2; }
        __syncthreads();
        if (tid == 0) {
            float gs = rv[0];
            int gi = ri[0];
#pragma unroll
            for (int t2 = 1; t2 < 4; ++t2)
                if (rv[t2] > gs || (rv[t2] == gs && ri[t2] < gi)) { gs = rv[t2]; gi = ri[t2]; }
            ks[pr] = gi;
            const float xnp = xnp4[pr] + xnp4[64 + pr] + xnp4[128 + pr] + xnp4[192 + pr];
            lv[pr] = xnp + 1024.0f - 2.0f * gs;   // exact score
        }
        __syncthreads();
    }

    // ---- idx out + block loss add + ticketed grid finalize ----
    if (tid < 64) {
        out[OFF_IDX + n0 + tid] = (float)ks[tid];
        float lc = lv[tid];
#pragma unroll
        for (int off = 32; off > 0; off >>= 1) lc += __shfl_down(lc, off, 64);
        if (tid == 0) {
            atomicAdd(sum, lc);
            __threadfence();
            const unsigned old = atomicAdd(tick, 1u);
            if (old == (unsigned)(gridDim.x - 1)) {
                const float s = atomicAdd(sum, 0.0f);
                const float m = s * (1.0f / (float)TOTAL);
                out[OFF_L1] = m;   // dictionary_loss
                out[OFF_L2] = m;   // commitment_loss (numerically identical)
            }
        }
    }

    // ---- quantize epilogue: reconstruct e from bf16 hi+lo (err <= ~3e-5) ----
    {
        const int pe = tid & 63, dqr = tid >> 6;
        const int kp = ks[pe];
        const int kx = (kp & 7) << 3;
        float qa[16];
#pragma unroll
        for (int g = 0; g < 2; ++g) {
            const int pos = kp * 64 + ((dqr * 16 + g * 8) ^ kx);
            const short8 h8 = *(const short8*)(ehT + pos);
            const short8 l8 = *(const short8*)(elT + pos);
#pragma unroll
            for (int j = 0; j < 8; ++j)
                qa[g * 8 + j] = bf16_to_f((unsigned short)h8[j]) + bf16_to_f((unsigned short)l8[j]);
        }
        float* ob = out + ((b * DD + dqr * 16) << 12) + hw0 + pe;
#pragma unroll
        for (int s = 0; s < 16; ++s) ob[s << 12] = qa[s];
    }
}

extern "C" void kernel_launch(void* const* d_in, const int* in_sizes, int n_in,
                              void* d_out, int out_size, void* d_ws, size_t ws_size,
                              hipStream_t stream) {
    const float* x = (const float*)d_in[0];      // [16,64,64,64]
    const float* e = (const float*)d_in[1];      // [64,1024]
    float* out = (float*)d_out;

    float* sum = (float*)d_ws;
    unsigned* tick = (unsigned*)d_ws + 2;
    float* enh = (float*)d_ws + WS_ENH_F;
    unsigned short* ehT = (unsigned short*)((char*)d_ws + WS_EHT_BYTE);
    unsigned short* elT = (unsigned short*)((char*)d_ws + WS_ELT_BYTE);

    prep_kernel<<<256, 256, 0, stream>>>(e, enh, ehT, elT, sum, tick);
    vq_gemm<<<NPTS / 64, 256, 0, stream>>>(x, e, enh, ehT, elT, out, sum, tick);
}

// Round 5
// 124.576 us; speedup vs baseline: 1.1789x; 1.1073x over previous
//
#include <hip/hip_runtime.h>

// VectorQuantizer: B=16, D=64, H=64, W=64, K=1024
#define DD 64
#define KK 1024
#define NPTS 65536
#define TOTAL 4194304

// Output layout (flat f32): quantized[4194304], L1, L2, idx[65536]
#define OFF_L1 4194304
#define OFF_L2 4194305
#define OFF_IDX 4194306

// ws layout (bytes): [0] f32 sum, [8] u32 ticket, enh @ float 64 (byte 256),
// ehT @ byte 65536 (128KB), elT @ byte 196608 (128KB). (<=328KB used)
#define WS_ENH_F 64
#define WS_EHT_BYTE 65536
#define WS_ELT_BYTE (65536 + 131072)

// score = dot(x,e) + 512 - ||e||^2/2  (argmax == argmin distance; +512 keeps
// all scores positive so float bits are monotone -> packed uint compare).
// Rescue margin: 64-ulp granule (<=4.6e-3) + bf16x3 err (~6e-4) + slack.
#define MARGIN_S 0.008f

typedef __attribute__((ext_vector_type(8))) short short8;
typedef __attribute__((ext_vector_type(4))) float f32x4;

__device__ __forceinline__ unsigned short bf16_rne(float f) {
    unsigned b = __float_as_uint(f);
    return (unsigned short)((b + 0x7FFFu + ((b >> 16) & 1u)) >> 16);
}
__device__ __forceinline__ float bf16_to_f(unsigned short h) {
    return __uint_as_float(((unsigned)h) << 16);
}
__device__ __forceinline__ unsigned umax(unsigned a, unsigned b) { return a > b ? a : b; }
__device__ __forceinline__ unsigned umin(unsigned a, unsigned b) { return a < b ? a : b; }
// async global->LDS DMA, 16B per lane; LDS dest = wave-uniform base + lane*16
__device__ __forceinline__ void gld_lds16(const void* g, void* l) {
    __builtin_amdgcn_global_load_lds(
        (const __attribute__((address_space(1))) void*)g,
        (__attribute__((address_space(3))) void*)l, 16, 0, 0);
}
// swizzled position of element d within a 64-elem row r (16B-granule XOR key)
__device__ __forceinline__ int swz(int r, int d) {
    return ((d & ~7) ^ ((r & 7) << 3)) | (d & 7);
}

// ---------- kernel 1: enh + swizzled bf16 hi/lo codebook [k][64] ----------
__global__ __launch_bounds__(256) void prep_kernel(const float* __restrict__ e,
                                                   float* __restrict__ enh,
                                                   unsigned short* __restrict__ ehT,
                                                   unsigned short* __restrict__ elT,
                                                   float* __restrict__ sum,
                                                   unsigned* __restrict__ tick) {
    const int tid = threadIdx.x;
    if (blockIdx.x == 0 && tid == 0) { *sum = 0.f; *tick = 0u; }
    const int wave = tid >> 6, lane = tid & 63;
    const int k = blockIdx.x * 4 + wave;      // this wave's code
    const float v = e[lane * KK + k];         // lane = d
    const unsigned short h = bf16_rne(v);
    const unsigned short l = bf16_rne(v - bf16_to_f(h));
    const int pos = k * 64 + swz(k, lane);
    ehT[pos] = h;
    elT[pos] = l;
    float s2 = v * v;
#pragma unroll
    for (int m = 32; m > 0; m >>= 1) s2 += __shfl_down(s2, m, 64);
    if (lane == 0) enh[k] = 512.0f - 0.5f * s2;
}

// ---------- kernel 2: 128-pt blocks. MFMA bf16x3 + packed-key argmax +
//            in-block exact rescue + quantize + loss via score identity ----------
// WHY 128 pts: the binding constraint is codebook re-broadcast from L2 --
// every block streams the full 256KB codebook. Evidence: 3 blocks/CU = 17.9
// GB/s/CU (58.5us), 4 blocks/CU = 13.5 GB/s/CU (77.7us) -- more residency
// LOWERED the aggregate rate (hot 16KB tile window, all blocks in lockstep).
// 128-pt blocks (grid 512) HALVE total codebook traffic and double per-tile
// compute per wave. Hot loop structure = the measured-58.5us r0 pattern
// verbatim (double-buffered global_load_lds + per-tile __syncthreads).
// Lessons kept: NO __launch_bounds__ min-waves (spills); NO hand vmcnt/
// sched_barrier (m141). Each wave = 32 pts x all 64 codes of a tile ->
// no cross-wave code-half merge phase at all.
// LDS = 32KB ebuf + 32KB xbuf + 1KB xnp2 -> 2 blocks/CU; grid = 2/CU exactly.
__global__ __launch_bounds__(256) void vq_gemm(const float* __restrict__ x,
                                               const float* __restrict__ e,
                                               const float* __restrict__ enh,
                                               const unsigned short* __restrict__ ehT,
                                               const unsigned short* __restrict__ elT,
                                               float* __restrict__ out,
                                               float* __restrict__ sum,
                                               unsigned* __restrict__ tick) {
    __shared__ __align__(16) char ebuf[2 * 16384];   // 32KB codebook double buffer
    __shared__ __align__(16) char xbuf[32768];       // 32KB x bf16 hi/lo (prologue)
    __shared__ float xnp2[256];                      // 1KB ||x||^2 partials

    // x fragments (prologue only; dead after A-frag register loads)
    unsigned short* xbh = (unsigned short*)xbuf;     // [128*64]
    unsigned short* xbl = xbh + 128 * 64;
    // post-loop aliases into xbuf (first write is after the post-loop barrier)
    int*   ks  = (int*)xbuf;            // [128] chosen code per point
    float* lv  = (float*)(ks + 128);    // [128] per-point loss term
    float* xp  = lv + 128;              // [64]  rescue point (fp32)
    int*   rl  = (int*)(xp + 64);       // [128] ambiguous-point list
    int*   rn  = rl + 128;              // [1]
    float* rv  = (float*)(rn + 1);      // [4]
    int*   ri  = (int*)(rv + 4);        // [4]
    float* red = (float*)(ri + 4);      // [2]

    const int tid = threadIdx.x;
    const int wave = tid >> 6, lane = tid & 63;
    const int n0 = blockIdx.x * 128;
    const int b = n0 >> 12;
    const int hw0 = n0 & 4095;

    const char* ehTb = (const char*)ehT;
    const char* elTb = (const char*)elT;
    const int lofs = wave * 1024 + lane * 16;   // per-lane byte offset in a pass

    // issue tile-0 DMA into buf0 immediately (lands during x-prep)
    {
        char* db = ebuf;
        gld_lds16(ehTb + lofs,        db + wave * 1024);
        gld_lds16(ehTb + 4096 + lofs, db + 4096 + wave * 1024);
        gld_lds16(elTb + lofs,        db + 8192 + wave * 1024);
        gld_lds16(elTb + 4096 + lofs, db + 12288 + wave * 1024);
    }

    // ---- x prep: coalesced global->reg, bf16 hi/lo pack into xbuf.
    // thread t: point p = t&127, d-half dg = t>>7 (32 d's each).
    {
        const int p = tid & 127, dg = tid >> 7;
        const float* xs = x + ((b * DD + dg * 32) << 12) + hw0 + p;
        float xv[32];
        float xn = 0.f;
#pragma unroll
        for (int s = 0; s < 32; ++s) {
            xv[s] = xs[s << 12];            // 256B coalesced per (wave,s)
            xn = fmaf(xv[s], xv[s], xn);
        }
        xnp2[tid] = xn;                     // partial over this half's 32 d's
#pragma unroll
        for (int g = 0; g < 4; ++g) {
            short8 hh, ll;
#pragma unroll
            for (int j = 0; j < 8; ++j) {
                const float f = xv[g * 8 + j];
                const unsigned short h = bf16_rne(f);
                hh[j] = (short)h;
                ll[j] = (short)bf16_rne(f - bf16_to_f(h));
            }
            const int d0 = dg * 32 + g * 8;
            const int pos = p * 64 + (d0 ^ ((p & 7) << 3));
            *(short8*)(xbh + pos) = hh;
            *(short8*)(xbl + pos) = ll;
        }
    }
    __syncthreads();   // x-bf16 visible to all waves

    const int ln15 = lane & 15, q8 = (lane >> 4) * 8;
    const int wp = wave * 32;          // this wave's point base (32 pts, ALL codes)

    short8 ah[2][2], al[2][2];         // persistent A frags [rf][kc]
#pragma unroll
    for (int rf = 0; rf < 2; ++rf)
#pragma unroll
        for (int kc = 0; kc < 2; ++kc) {
            const int pp = wp + rf * 16 + ln15;
            const int pos = pp * 64 + ((kc * 32 + q8) ^ ((pp & 7) << 3));
            ah[rf][kc] = *(const short8*)(xbh + pos);
            al[rf][kc] = *(const short8*)(xbl + pos);
        }
    // xbuf is now dead as frag storage (frags in regs); aliases written only
    // after the post-loop barrier.

    unsigned v1u[8], v2u[8];
#pragma unroll
    for (int r = 0; r < 8; ++r) { v1u[r] = 0u; v2u[r] = 0u; }

    for (int kt = 0; kt < 16; ++kt) {
        __syncthreads();   // drains tile-kt DMA + all waves done with kt-1
        if (kt < 15) {     // stream tile kt+1 into the other buffer
            const int nkt = kt + 1;
            char* db = ebuf + (nkt & 1) * 16384;
            const char* sH = ehTb + nkt * 8192 + lofs;
            const char* sL = elTb + nkt * 8192 + lofs;
            gld_lds16(sH,        db + wave * 1024);
            gld_lds16(sH + 4096, db + 4096 + wave * 1024);
            gld_lds16(sL,        db + 8192 + wave * 1024);
            gld_lds16(sL + 4096, db + 12288 + wave * 1024);
        }
        const unsigned short* ebH = (const unsigned short*)(ebuf + (kt & 1) * 16384);
        const unsigned short* ebL = ebH + 4096;

        // acc init = 512 - ||e||^2/2 (biased argmax score)
        f32x4 acc[2][4];
#pragma unroll
        for (int cf = 0; cf < 4; ++cf) {
            const float ec = enh[kt * 64 + cf * 16 + ln15];
#pragma unroll
            for (int rf = 0; rf < 2; ++rf)
                acc[rf][cf] = (f32x4){ec, ec, ec, ec};
        }

#pragma unroll
        for (int kc = 0; kc < 2; ++kc) {
            short8 bh[4], bl[4];
#pragma unroll
            for (int cf = 0; cf < 4; ++cf) {
                const int c = cf * 16 + ln15;
                const int pos = c * 64 + ((kc * 32 + q8) ^ ((c & 7) << 3));
                bh[cf] = *(const short8*)(ebH + pos);
                bl[cf] = *(const short8*)(ebL + pos);
            }
#pragma unroll
            for (int rf = 0; rf < 2; ++rf)
#pragma unroll
                for (int cf = 0; cf < 4; ++cf) {
                    acc[rf][cf] = __builtin_amdgcn_mfma_f32_16x16x32_bf16(al[rf][kc], bh[cf], acc[rf][cf], 0, 0, 0);
                    acc[rf][cf] = __builtin_amdgcn_mfma_f32_16x16x32_bf16(ah[rf][kc], bl[cf], acc[rf][cf], 0, 0, 0);
                    acc[rf][cf] = __builtin_amdgcn_mfma_f32_16x16x32_bf16(ah[rf][kc], bh[cf], acc[rf][cf], 0, 0, 0);
                }
        }

        // packed-key top-2 per (rf,reg) row: key = (bits|63) ^ (kt*4+cf)
        // (low6 = 63^col6 -> umax tie-breaks toward SMALLER col6 = smaller k)
#pragma unroll
        for (int rf = 0; rf < 2; ++rf)
#pragma unroll
            for (int reg = 0; reg < 4; ++reg) {
                const int r = rf * 4 + reg;
                const unsigned k0 = (__float_as_uint(acc[rf][0][reg]) | 63u) ^ (unsigned)(kt * 4 + 0);
                const unsigned k1 = (__float_as_uint(acc[rf][1][reg]) | 63u) ^ (unsigned)(kt * 4 + 1);
                const unsigned k2 = (__float_as_uint(acc[rf][2][reg]) | 63u) ^ (unsigned)(kt * 4 + 2);
                const unsigned k3 = (__float_as_uint(acc[rf][3][reg]) | 63u) ^ (unsigned)(kt * 4 + 3);
                unsigned a = umax(k0, k1), bb = umin(k0, k1);
                v2u[r] = umax(umax(v2u[r], umin(v1u[r], a)), bb);
                v1u[r] = umax(v1u[r], a);
                a = umax(k2, k3); bb = umin(k2, k3);
                v2u[r] = umax(umax(v2u[r], umin(v1u[r], a)), bb);
                v1u[r] = umax(v1u[r], a);
            }
    }

    __syncthreads();   // all waves done with tile 15 -> xbuf aliases safe
    if (tid == 0) *rn = 0;
    __syncthreads();

    // decode + cross-lane merge within the 16 lanes sharing each row-set.
    // Each wave covers ALL codes for its 32 pts -> result is final per point.
#pragma unroll
    for (int r = 0; r < 8; ++r) {
        const unsigned c6 = 63u - (v1u[r] & 63u);
        int col = (int)(c6 >> 2) * 64 + (int)(c6 & 3) * 16 + ln15;
        float val = __uint_as_float(v1u[r] & ~63u);
        float sec = __uint_as_float(v2u[r] & ~63u);
#pragma unroll
        for (int msk = 1; msk < 16; msk <<= 1) {
            const float ov = __shfl_xor(val, msk);
            const int oc = __shfl_xor(col, msk);
            const float os = __shfl_xor(sec, msk);
            sec = fmaxf(fmaxf(sec, os), fminf(val, ov));
            const bool t = (ov > val) || (ov == val && oc < col);
            val = t ? ov : val;
            col = t ? oc : col;
        }
        if (ln15 == 0) {
            const int q = lane >> 4;
            const int pt = wp + (r >> 2) * 16 + q * 4 + (r & 3);
            ks[pt] = col;
            // loss via identity: ||x-e||^2 = ||x||^2 + 1024 - 2*score
            // midpoint decode (|32 = half the 64-ulp granule) -> unbiased
            const float xnp = xnp2[pt] + xnp2[128 + pt];
            const float bmid = __uint_as_float(__float_as_uint(val) | 32u);
            lv[pt] = xnp + 1024.0f - 2.0f * bmid;
            if (val - sec < MARGIN_S) {   // ambiguous under granule+bf16x3 bound
                const int w = atomicAdd(rn, 1);
                rl[w] = pt;               // <=128 entries possible
            }
        }
    }
    __syncthreads();

    // ---- in-block exact fp32 rescue (expected ~0.3 items/block) ----
    const int lcnt = *rn;
    for (int it = 0; it < lcnt; ++it) {
        const int pr = rl[it];
        if (tid < 64) xp[tid] = x[((b * DD + tid) << 12) + hw0 + pr];
        __syncthreads();
        float d0 = 0.f, d1 = 0.f, d2 = 0.f, d3 = 0.f;
#pragma unroll 8
        for (int dd = 0; dd < DD; ++dd) {
            const float xd = xp[dd];
            const float4 ev = *(const float4*)(e + dd * KK + tid * 4);
            d0 = fmaf(xd, ev.x, d0);
            d1 = fmaf(xd, ev.y, d1);
            d2 = fmaf(xd, ev.z, d2);
            d3 = fmaf(xd, ev.w, d3);
        }
        const float4 ea = *(const float4*)(enh + tid * 4);
        float bs = d0 + ea.x;
        int bi2 = tid * 4;
        if (d1 + ea.y > bs) { bs = d1 + ea.y; bi2 = tid * 4 + 1; }
        if (d2 + ea.z > bs) { bs = d2 + ea.z; bi2 = tid * 4 + 2; }
        if (d3 + ea.w > bs) { bs = d3 + ea.w; bi2 = tid * 4 + 3; }
#pragma unroll
        for (int m = 1; m < 64; m <<= 1) {
            const float ov = __shfl_xor(bs, m, 64);
            const int oi = __shfl_xor(bi2, m, 64);
            if (ov > bs || (ov == bs && oi < bi2)) { bs = ov; bi2 = oi; }
        }
        if (lane == 0) { rv[wave] = bs; ri[wave] = bi2; }
        __syncthreads();
        if (tid == 0) {
            float gs = rv[0];
            int gi = ri[0];
#pragma unroll
            for (int t2 = 1; t2 < 4; ++t2)
                if (rv[t2] > gs || (rv[t2] == gs && ri[t2] < gi)) { gs = rv[t2]; gi = ri[t2]; }
            ks[pr] = gi;
            const float xnp = xnp2[pr] + xnp2[128 + pr];
            lv[pr] = xnp + 1024.0f - 2.0f * gs;   // exact score
        }
        __syncthreads();
    }

    // ---- idx out + block loss partials ----
    if (tid < 128) {   // waves 0,1
        out[OFF_IDX + n0 + tid] = (float)ks[tid];
        float lc = lv[tid];
#pragma unroll
        for (int off = 32; off > 0; off >>= 1) lc += __shfl_down(lc, off, 64);
        if (lane == 0) red[wave] = lc;
    }
    __syncthreads();
    if (tid == 0) {   // block loss add + ticketed grid finalize
        atomicAdd(sum, red[0] + red[1]);
        __threadfence();
        const unsigned old = atomicAdd(tick, 1u);
        if (old == (unsigned)(gridDim.x - 1)) {
            const float s = atomicAdd(sum, 0.0f);
            const float m = s * (1.0f / (float)TOTAL);
            out[OFF_L1] = m;   // dictionary_loss
            out[OFF_L2] = m;   // commitment_loss (numerically identical)
        }
    }

    // ---- quantize epilogue: reconstruct e from bf16 hi+lo (err <= ~3e-5) ----
    {
        const int pe = tid & 127, dh = tid >> 7;   // 32 d's per thread
        const int kp = ks[pe];
        const int kx = (kp & 7) << 3;
        float qa[32];
#pragma unroll
        for (int g = 0; g < 4; ++g) {
            const int pos = kp * 64 + ((dh * 32 + g * 8) ^ kx);
            const short8 h8 = *(const short8*)(ehT + pos);
            const short8 l8 = *(const short8*)(elT + pos);
#pragma unroll
            for (int j = 0; j < 8; ++j)
                qa[g * 8 + j] = bf16_to_f((unsigned short)h8[j]) + bf16_to_f((unsigned short)l8[j]);
        }
        float* ob = out + ((b * DD + dh * 32) << 12) + hw0 + pe;
#pragma unroll
        for (int s = 0; s < 32; ++s) ob[s << 12] = qa[s];
    }
}

extern "C" void kernel_launch(void* const* d_in, const int* in_sizes, int n_in,
                              void* d_out, int out_size, void* d_ws, size_t ws_size,
                              hipStream_t stream) {
    const float* x = (const float*)d_in[0];      // [16,64,64,64]
    const float* e = (const float*)d_in[1];      // [64,1024]
    float* out = (float*)d_out;

    float* sum = (float*)d_ws;
    unsigned* tick = (unsigned*)d_ws + 2;
    float* enh = (float*)d_ws + WS_ENH_F;
    unsigned short* ehT = (unsigned short*)((char*)d_ws + WS_EHT_BYTE);
    unsigned short* elT = (unsigned short*)((char*)d_ws + WS_ELT_BYTE);

    prep_kernel<<<256, 256, 0, stream>>>(e, enh, ehT, elT, sum, tick);
    vq_gemm<<<NPTS / 128, 256, 0, stream>>>(x, e, enh, ehT, elT, out, sum, tick);
}

// Round 6
// 121.475 us; speedup vs baseline: 1.2090x; 1.0255x over previous
//
#include <hip/hip_runtime.h>

// VectorQuantizer: B=16, D=64, H=64, W=64, K=1024
#define DD 64
#define KK 1024
#define NPTS 65536
#define TOTAL 4194304

// Output layout (flat f32): quantized[4194304], L1, L2, idx[65536]
#define OFF_L1 4194304
#define OFF_L2 4194305
#define OFF_IDX 4194306

// ws layout (bytes): [0] f32 sum, [8] u32 ticket, enh @ float 64 (byte 256),
// ehT @ byte 65536 (128KB), elT @ byte 196608 (128KB). (<=328KB used)
#define WS_ENH_F 64
#define WS_EHT_BYTE 65536
#define WS_ELT_BYTE (65536 + 131072)

// score = dot(x,e) + 512 - ||e||^2/2  (argmax == argmin distance; +512 keeps
// all scores positive so float bits are monotone -> packed uint compare).
// Rescue margin: 64-ulp granule (<=4.6e-3) + bf16x3 err (~6e-4) + slack.
#define MARGIN_S 0.008f

typedef __attribute__((ext_vector_type(8))) short short8;
typedef __attribute__((ext_vector_type(4))) float f32x4;

__device__ __forceinline__ unsigned short bf16_rne(float f) {
    unsigned b = __float_as_uint(f);
    return (unsigned short)((b + 0x7FFFu + ((b >> 16) & 1u)) >> 16);
}
__device__ __forceinline__ float bf16_to_f(unsigned short h) {
    return __uint_as_float(((unsigned)h) << 16);
}
__device__ __forceinline__ unsigned umax(unsigned a, unsigned b) { return a > b ? a : b; }
__device__ __forceinline__ unsigned umin(unsigned a, unsigned b) { return a < b ? a : b; }
// async global->LDS DMA, 16B per lane; LDS dest = wave-uniform base + lane*16
// (HW adds lane*16 to the LDS dest; the SOURCE must carry lane*16 explicitly)
__device__ __forceinline__ void gld_lds16(const void* g, void* l) {
    __builtin_amdgcn_global_load_lds(
        (const __attribute__((address_space(1))) void*)g,
        (__attribute__((address_space(3))) void*)l, 16, 0, 0);
}
// swizzled position of element d within a 64-elem row r (16B-granule XOR key)
__device__ __forceinline__ int swz(int r, int d) {
    return ((d & ~7) ^ ((r & 7) << 3)) | (d & 7);
}

// stage one codebook quarter (256 codes, hi 32KB + lo 32KB) into LDS cb
__device__ __forceinline__ void stage_quarter(const char* ehTb, const char* elTb,
                                              char* cb, int q, int wave, int lane) {
    const int off = wave * 8192 + lane * 16;
    const char* sH = ehTb + q * 32768 + off;
    const char* sL = elTb + q * 32768 + off;
    char* dH = cb + wave * 8192;
    char* dL = cb + 32768 + wave * 8192;
#pragma unroll
    for (int j = 0; j < 8; ++j) {
        gld_lds16(sH + j * 1024, dH + j * 1024);
        gld_lds16(sL + j * 1024, dL + j * 1024);
    }
}

// ---------- kernel 1: enh + swizzled bf16 hi/lo codebook [k][64] ----------
// Coalesced rewrite: old version read e column-wise (64 lanes @ stride 4KB =
// 64 scattered 64B txns per wave, 65536 total). Now: block bk owns 64 codes;
// wave w reads d-range [w*16,w*16+16) k-contiguous (256B coalesced), packs
// bf16 hi/lo into an LDS tile, writes the 8KB tile out linearly.
__global__ __launch_bounds__(256) void prep_kernel(const float* __restrict__ e,
                                                   float* __restrict__ enh,
                                                   unsigned short* __restrict__ ehT,
                                                   unsigned short* __restrict__ elT,
                                                   float* __restrict__ sum,
                                                   unsigned* __restrict__ tick) {
    __shared__ unsigned short tH[64 * 64];   // 8KB [code_local][swz d]
    __shared__ unsigned short tL[64 * 64];
    __shared__ float ps[4 * 64];
    const int tid = threadIdx.x, wave = tid >> 6, lane = tid & 63;
    if (blockIdx.x == 0 && tid == 0) { *sum = 0.f; *tick = 0u; }
    const int k = blockIdx.x * 64 + lane;    // this thread's code
    float s2 = 0.f;
    short8 hh[2], ll[2];
#pragma unroll
    for (int g = 0; g < 2; ++g)
#pragma unroll
        for (int j = 0; j < 8; ++j) {
            const int d = wave * 16 + g * 8 + j;
            const float v = e[d * KK + k];   // lanes k-contiguous -> 256B coalesced
            const unsigned short h = bf16_rne(v);
            hh[g][j] = (short)h;
            ll[g][j] = (short)bf16_rne(v - bf16_to_f(h));
            s2 = fmaf(v, v, s2);
        }
    ps[wave * 64 + lane] = s2;
#pragma unroll
    for (int g = 0; g < 2; ++g) {
        const int pos = lane * 64 + ((wave * 16 + g * 8) ^ ((k & 7) << 3));
        *(short8*)(tH + pos) = hh[g];
        *(short8*)(tL + pos) = ll[g];
    }
    __syncthreads();
    if (wave == 0) {
        const float t = ps[lane] + ps[64 + lane] + ps[128 + lane] + ps[192 + lane];
        enh[k] = 512.0f - 0.5f * t;
    }
    // bulk coalesced write-out: 8KB per table, 32B per thread
    {
        const short8* srcH = (const short8*)tH;
        const short8* srcL = (const short8*)tL;
        short8* dstH = (short8*)(ehT + blockIdx.x * 64 * 64);
        short8* dstL = (short8*)(elT + blockIdx.x * 64 * 64);
        dstH[tid * 2]     = srcH[tid * 2];
        dstH[tid * 2 + 1] = srcH[tid * 2 + 1];
        dstL[tid * 2]     = srcL[tid * 2];
        dstL[tid * 2 + 1] = srcL[tid * 2 + 1];
    }
}

// ---------- kernel 2: QUARTER-RESIDENT codebook. MFMA bf16x3 + packed-key
//            argmax + in-block exact rescue + quantize + loss identity ----------
// WHY: every streamed variant (r0..r5: 58-80us) was bound by 16 per-tile
// {__syncthreads -> vmcnt(0) drain} convoys, invariant to traffic/residency/
// VGPRs. This version holds 256 codes (64KB hi+lo) RESIDENT in LDS and runs
// 4 barrier-free sub-steps (192 MFMA/wave) per quarter; only 4 bulk DMA waits
// per block. The other co-resident block absorbs the stall (unsynchronized).
// 128 pts/block, grid 512 = 2 blocks/CU exactly. Lessons kept: NO
// __launch_bounds__ min-waves (spills), NO hand vmcnt/sched_barrier (m141).
// LDS = 64KB cb + 1KB xnp2 = 66560 -> 2 blocks/CU. x-frags stage inside cb
// BEFORE the first DMA (dead after A-frag reg loads).
__global__ __launch_bounds__(256) void vq_gemm(const float* __restrict__ x,
                                               const float* __restrict__ e,
                                               const float* __restrict__ enh,
                                               const unsigned short* __restrict__ ehT,
                                               const unsigned short* __restrict__ elT,
                                               float* __restrict__ out,
                                               float* __restrict__ sum,
                                               unsigned* __restrict__ tick) {
    __shared__ __align__(16) char cb[65536];   // resident quarter: hi 32KB | lo 32KB
    __shared__ float xnp2[256];                // 1KB ||x||^2 partials

    // prologue x-frag staging inside cb (dead before first DMA)
    unsigned short* xbh = (unsigned short*)cb;           // 16KB
    unsigned short* xbl = (unsigned short*)(cb + 16384); // 16KB
    // post-loop aliases into cb (first write after the post-loop barrier)
    int*   ks  = (int*)cb;              // [128] chosen code per point
    float* lv  = (float*)(ks + 128);    // [128] per-point loss term
    float* xp  = lv + 128;              // [64]  rescue point (fp32)
    int*   rl  = (int*)(xp + 64);       // [128] ambiguous-point list
    int*   rn  = rl + 128;              // [1]
    float* rv  = (float*)(rn + 1);      // [4]
    int*   ri  = (int*)(rv + 4);        // [4]
    float* red = (float*)(ri + 4);      // [2]

    const int tid = threadIdx.x;
    const int wave = tid >> 6, lane = tid & 63;
    const int n0 = blockIdx.x * 128;
    const int b = n0 >> 12;
    const int hw0 = n0 & 4095;

    const char* ehTb = (const char*)ehT;
    const char* elTb = (const char*)elT;

    // ---- x prep: coalesced global->reg, bf16 hi/lo pack into cb-as-xbuf.
    // thread t: point p = t&127, d-half dg = t>>7 (32 d's each).
    {
        const int p = tid & 127, dg = tid >> 7;
        const float* xs = x + ((b * DD + dg * 32) << 12) + hw0 + p;
        float xv[32];
        float xn = 0.f;
#pragma unroll
        for (int s = 0; s < 32; ++s) {
            xv[s] = xs[s << 12];            // 256B coalesced per (wave,s)
            xn = fmaf(xv[s], xv[s], xn);
        }
        xnp2[tid] = xn;                     // partial over this half's 32 d's
#pragma unroll
        for (int g = 0; g < 4; ++g) {
            short8 hh, ll;
#pragma unroll
            for (int j = 0; j < 8; ++j) {
                const float f = xv[g * 8 + j];
                const unsigned short h = bf16_rne(f);
                hh[j] = (short)h;
                ll[j] = (short)bf16_rne(f - bf16_to_f(h));
            }
            const int d0 = dg * 32 + g * 8;
            const int pos = p * 64 + (d0 ^ ((p & 7) << 3));
            *(short8*)(xbh + pos) = hh;
            *(short8*)(xbl + pos) = ll;
        }
    }
    __syncthreads();   // x-bf16 visible to all waves

    const int ln15 = lane & 15, q8 = (lane >> 4) * 8;
    const int wp = wave * 32;          // this wave's point base (32 pts, ALL codes)

    short8 ah[2][2], al[2][2];         // persistent A frags [rf][kc]
#pragma unroll
    for (int rf = 0; rf < 2; ++rf)
#pragma unroll
        for (int kc = 0; kc < 2; ++kc) {
            const int pp = wp + rf * 16 + ln15;
            const int pos = pp * 64 + ((kc * 32 + q8) ^ ((pp & 7) << 3));
            ah[rf][kc] = *(const short8*)(xbh + pos);
            al[rf][kc] = *(const short8*)(xbl + pos);
        }
    __syncthreads();   // frags in regs everywhere; cb free for quarter-0 DMA

    stage_quarter(ehTb, elTb, cb, 0, wave, lane);

    unsigned v1u[8], v2u[8];
#pragma unroll
    for (int r = 0; r < 8; ++r) { v1u[r] = 0u; v2u[r] = 0u; }

    const unsigned short* cbH = (const unsigned short*)cb;
    const unsigned short* cbL = (const unsigned short*)(cb + 32768);

    for (int q = 0; q < 4; ++q) {
        __syncthreads();   // drains DMA(q) (compiler vmcnt0 before barrier)

        // 4 barrier-free sub-steps over the resident quarter (64 codes each)
#pragma unroll
        for (int ct = 0; ct < 4; ++ct) {
            const int tile = q * 4 + ct;   // global code-tile 0..15

            // acc init = 512 - ||e||^2/2 (biased argmax score)
            f32x4 acc[2][4];
#pragma unroll
            for (int cf = 0; cf < 4; ++cf) {
                const float ec = enh[tile * 64 + cf * 16 + ln15];
#pragma unroll
                for (int rf = 0; rf < 2; ++rf)
                    acc[rf][cf] = (f32x4){ec, ec, ec, ec};
            }

#pragma unroll
            for (int kc = 0; kc < 2; ++kc) {
                short8 bh[4], bl[4];
#pragma unroll
                for (int cf = 0; cf < 4; ++cf) {
                    const int c = ct * 64 + cf * 16 + ln15;   // local code in quarter
                    const int pos = c * 64 + ((kc * 32 + q8) ^ ((c & 7) << 3));
                    bh[cf] = *(const short8*)(cbH + pos);
                    bl[cf] = *(const short8*)(cbL + pos);
                }
#pragma unroll
                for (int rf = 0; rf < 2; ++rf)
#pragma unroll
                    for (int cf = 0; cf < 4; ++cf) {
                        acc[rf][cf] = __builtin_amdgcn_mfma_f32_16x16x32_bf16(al[rf][kc], bh[cf], acc[rf][cf], 0, 0, 0);
                        acc[rf][cf] = __builtin_amdgcn_mfma_f32_16x16x32_bf16(ah[rf][kc], bl[cf], acc[rf][cf], 0, 0, 0);
                        acc[rf][cf] = __builtin_amdgcn_mfma_f32_16x16x32_bf16(ah[rf][kc], bh[cf], acc[rf][cf], 0, 0, 0);
                    }
            }

            // packed-key top-2 per (rf,reg) row: key = (bits|63) ^ (tile*4+cf)
            // (low6 = 63^col6 -> umax tie-breaks toward SMALLER col6 = smaller k)
#pragma unroll
            for (int rf = 0; rf < 2; ++rf)
#pragma unroll
                for (int reg = 0; reg < 4; ++reg) {
                    const int r = rf * 4 + reg;
                    const unsigned k0 = (__float_as_uint(acc[rf][0][reg]) | 63u) ^ (unsigned)(tile * 4 + 0);
                    const unsigned k1 = (__float_as_uint(acc[rf][1][reg]) | 63u) ^ (unsigned)(tile * 4 + 1);
                    const unsigned k2 = (__float_as_uint(acc[rf][2][reg]) | 63u) ^ (unsigned)(tile * 4 + 2);
                    const unsigned k3 = (__float_as_uint(acc[rf][3][reg]) | 63u) ^ (unsigned)(tile * 4 + 3);
                    unsigned a = umax(k0, k1), bb = umin(k0, k1);
                    v2u[r] = umax(umax(v2u[r], umin(v1u[r], a)), bb);
                    v1u[r] = umax(v1u[r], a);
                    a = umax(k2, k3); bb = umin(k2, k3);
                    v2u[r] = umax(umax(v2u[r], umin(v1u[r], a)), bb);
                    v1u[r] = umax(v1u[r], a);
                }
        }

        __syncthreads();   // all waves done reading quarter q
        if (q < 3) stage_quarter(ehTb, elTb, cb, q + 1, wave, lane);
    }

    // cb is dead (post-compute barrier passed) -> aliases safe
    if (tid == 0) *rn = 0;
    __syncthreads();

    // decode + cross-lane merge within the 16 lanes sharing each row-set.
    // Each wave covers ALL codes for its 32 pts -> result is final per point.
#pragma unroll
    for (int r = 0; r < 8; ++r) {
        const unsigned c6 = 63u - (v1u[r] & 63u);
        int col = (int)(c6 >> 2) * 64 + (int)(c6 & 3) * 16 + ln15;
        float val = __uint_as_float(v1u[r] & ~63u);
        float sec = __uint_as_float(v2u[r] & ~63u);
#pragma unroll
        for (int msk = 1; msk < 16; msk <<= 1) {
            const float ov = __shfl_xor(val, msk);
            const int oc = __shfl_xor(col, msk);
            const float os = __shfl_xor(sec, msk);
            sec = fmaxf(fmaxf(sec, os), fminf(val, ov));
            const bool t = (ov > val) || (ov == val && oc < col);
            val = t ? ov : val;
            col = t ? oc : col;
        }
        if (ln15 == 0) {
            const int qq = lane >> 4;
            const int pt = wp + (r >> 2) * 16 + qq * 4 + (r & 3);
            ks[pt] = col;
            // loss via identity: ||x-e||^2 = ||x||^2 + 1024 - 2*score
            // midpoint decode (|32 = half the 64-ulp granule) -> unbiased
            const float xnp = xnp2[pt] + xnp2[128 + pt];
            const float bmid = __uint_as_float(__float_as_uint(val) | 32u);
            lv[pt] = xnp + 1024.0f - 2.0f * bmid;
            if (val - sec < MARGIN_S) {   // ambiguous under granule+bf16x3 bound
                const int w = atomicAdd(rn, 1);
                rl[w] = pt;               // <=128 entries possible
            }
        }
    }
    __syncthreads();

    // ---- in-block exact fp32 rescue (expected ~0.3 items/block) ----
    const int lcnt = *rn;
    for (int it = 0; it < lcnt; ++it) {
        const int pr = rl[it];
        if (tid < 64) xp[tid] = x[((b * DD + tid) << 12) + hw0 + pr];
        __syncthreads();
        float d0 = 0.f, d1 = 0.f, d2 = 0.f, d3 = 0.f;
#pragma unroll 8
        for (int dd = 0; dd < DD; ++dd) {
            const float xd = xp[dd];
            const float4 ev = *(const float4*)(e + dd * KK + tid * 4);
            d0 = fmaf(xd, ev.x, d0);
            d1 = fmaf(xd, ev.y, d1);
            d2 = fmaf(xd, ev.z, d2);
            d3 = fmaf(xd, ev.w, d3);
        }
        const float4 ea = *(const float4*)(enh + tid * 4);
        float bs = d0 + ea.x;
        int bi2 = tid * 4;
        if (d1 + ea.y > bs) { bs = d1 + ea.y; bi2 = tid * 4 + 1; }
        if (d2 + ea.z > bs) { bs = d2 + ea.z; bi2 = tid * 4 + 2; }
        if (d3 + ea.w > bs) { bs = d3 + ea.w; bi2 = tid * 4 + 3; }
#pragma unroll
        for (int m = 1; m < 64; m <<= 1) {
            const float ov = __shfl_xor(bs, m, 64);
            const int oi = __shfl_xor(bi2, m, 64);
            if (ov > bs || (ov == bs && oi < bi2)) { bs = ov; bi2 = oi; }
        }
        if (lane == 0) { rv[wave] = bs; ri[wave] = bi2; }
        __syncthreads();
        if (tid == 0) {
            float gs = rv[0];
            int gi = ri[0];
#pragma unroll
            for (int t2 = 1; t2 < 4; ++t2)
                if (rv[t2] > gs || (rv[t2] == gs && ri[t2] < gi)) { gs = rv[t2]; gi = ri[t2]; }
            ks[pr] = gi;
            const float xnp = xnp2[pr] + xnp2[128 + pr];
            lv[pr] = xnp + 1024.0f - 2.0f * gs;   // exact score
        }
        __syncthreads();
    }

    // ---- idx out + block loss partials ----
    if (tid < 128) {   // waves 0,1
        out[OFF_IDX + n0 + tid] = (float)ks[tid];
        float lc = lv[tid];
#pragma unroll
        for (int off = 32; off > 0; off >>= 1) lc += __shfl_down(lc, off, 64);
        if (lane == 0) red[wave] = lc;
    }
    __syncthreads();
    if (tid == 0) {   // block loss add + ticketed grid finalize
        atomicAdd(sum, red[0] + red[1]);
        __threadfence();
        const unsigned old = atomicAdd(tick, 1u);
        if (old == (unsigned)(gridDim.x - 1)) {
            const float s = atomicAdd(sum, 0.0f);
            const float m = s * (1.0f / (float)TOTAL);
            out[OFF_L1] = m;   // dictionary_loss
            out[OFF_L2] = m;   // commitment_loss (numerically identical)
        }
    }

    // ---- quantize epilogue: reconstruct e from bf16 hi+lo (err <= ~3e-5) ----
    {
        const int pe = tid & 127, dh = tid >> 7;   // 32 d's per thread
        const int kp = ks[pe];
        const int kx = (kp & 7) << 3;
        float qa[32];
#pragma unroll
        for (int g = 0; g < 4; ++g) {
            const int pos = kp * 64 + ((dh * 32 + g * 8) ^ kx);
            const short8 h8 = *(const short8*)(ehT + pos);
            const short8 l8 = *(const short8*)(elT + pos);
#pragma unroll
            for (int j = 0; j < 8; ++j)
                qa[g * 8 + j] = bf16_to_f((unsigned short)h8[j]) + bf16_to_f((unsigned short)l8[j]);
        }
        float* ob = out + ((b * DD + dh * 32) << 12) + hw0 + pe;
#pragma unroll
        for (int s = 0; s < 32; ++s) ob[s << 12] = qa[s];
    }
}

extern "C" void kernel_launch(void* const* d_in, const int* in_sizes, int n_in,
                              void* d_out, int out_size, void* d_ws, size_t ws_size,
                              hipStream_t stream) {
    const float* x = (const float*)d_in[0];      // [16,64,64,64]
    const float* e = (const float*)d_in[1];      // [64,1024]
    float* out = (float*)d_out;

    float* sum = (float*)d_ws;
    unsigned* tick = (unsigned*)d_ws + 2;
    float* enh = (float*)d_ws + WS_ENH_F;
    unsigned short* ehT = (unsigned short*)((char*)d_ws + WS_EHT_BYTE);
    unsigned short* elT = (unsigned short*)((char*)d_ws + WS_ELT_BYTE);

    prep_kernel<<<KK / 64, 256, 0, stream>>>(e, enh, ehT, elT, sum, tick);
    vq_gemm<<<NPTS / 128, 256, 0, stream>>>(x, e, enh, ehT, elT, out, sum, tick);
}